// Round 1
// baseline (2884.930 us; speedup 1.0000x reference)
//
#include <hip/hip_runtime.h>
#include <stdint.h>

// ---------------------------------------------------------------------------
// SimpleEdgeBlock: two FullyConnectedTensorProducts (64x0e+64x1o)^2 -> same,
// summed. Restructured as one bf16 MFMA GEMM:
//   rows   = 4 per edge  (out0, out1_i i=0..2)       M = 4E
//   cols   = w           N = 64
//   K      = 16384 = pair(2) x half(2) x v(64) x u(64)
// B (weights, scales folded) prepacked bf16 in d_ws as B[type][w][k].
// A (z = x[u]*y[v]) synthesized per chunk: x register-cached, y scalar from LDS.
// ---------------------------------------------------------------------------

typedef __attribute__((ext_vector_type(8))) short short8;   // 8 x bf16 (4 VGPR)
typedef __attribute__((ext_vector_type(16))) float f32x16;  // MFMA 32x32 acc
typedef unsigned short u16;

#define ETOT 100000

__device__ __forceinline__ unsigned pk2(float lo, float hi) {
  // pack hi16(lo), hi16(hi) -> one dword (bf16 truncation; bias cancels in sums)
  return __builtin_amdgcn_perm(__builtin_bit_cast(unsigned, hi),
                               __builtin_bit_cast(unsigned, lo), 0x07060302u);
}
__device__ __forceinline__ float bf2f(u16 s) {
  return __builtin_bit_cast(float, ((unsigned)s) << 16);
}
__device__ __forceinline__ void unpk8(short8 s, float f[8]) {
  uint4 u = __builtin_bit_cast(uint4, s);
  unsigned a[4] = {u.x, u.y, u.z, u.w};
#pragma unroll
  for (int jj = 0; jj < 4; ++jj) {
    f[2 * jj]     = __builtin_bit_cast(float, a[jj] << 16);
    f[2 * jj + 1] = __builtin_bit_cast(float, a[jj] & 0xffff0000u);
  }
}
__device__ __forceinline__ short8 scalepack(const float f[8], float ysc) {
  unsigned p0 = pk2(f[0] * ysc, f[1] * ysc);
  unsigned p1 = pk2(f[2] * ysc, f[3] * ysc);
  unsigned p2 = pk2(f[4] * ysc, f[5] * ysc);
  unsigned p3 = pk2(f[6] * ysc, f[7] * ysc);
  uint4 r = make_uint4(p0, p1, p2, p3);
  return __builtin_bit_cast(short8, r);
}
__device__ __forceinline__ short8 pack8(const float f[8]) {
  unsigned p0 = pk2(f[0], f[1]);
  unsigned p1 = pk2(f[2], f[3]);
  unsigned p2 = pk2(f[4], f[5]);
  unsigned p3 = pk2(f[6], f[7]);
  uint4 r = make_uint4(p0, p1, p2, p3);
  return __builtin_bit_cast(short8, r);
}

// ---------------------------------------------------------------------------
// Prep: W (fp32 [u][v][w]) -> B bf16 [t][w][k], k = p*8192 + half*4096 + v*64 + u
//   t=0: half0 = a0*W_000,      half1 = a0/sqrt3 * W_110
//   t=1: half0 = a1/sqrt3*W_011, half1 = a1/sqrt3 * W_101   (a0==a1)
// ---------------------------------------------------------------------------
__global__ void prep_B(const float* __restrict__ W10, const float* __restrict__ W11,
                       const float* __restrict__ W12, const float* __restrict__ W13,
                       const float* __restrict__ W20, const float* __restrict__ W21,
                       const float* __restrict__ W22, const float* __restrict__ W23,
                       u16* __restrict__ B) {
  int idx = blockIdx.x * 256 + threadIdx.x;  // 2*64*16384 = 2097152 total
  int k = idx & 16383;
  int w = (idx >> 14) & 63;
  int t = idx >> 20;
  int p = k >> 13;
  int half = (k >> 12) & 1;
  int v = (k >> 6) & 63;
  int u = k & 63;
  const float a0 = 0.011048543456039806f;            // 1/sqrt(2*64*64)
  const float a0s3 = a0 * 0.5773502691896258f;       // a0/sqrt(3)
  const float* Wsrc;
  float scale;
  if (t == 0) {
    Wsrc = half ? (p ? W21 : W11) : (p ? W20 : W10);
    scale = half ? a0s3 : a0;
  } else {
    Wsrc = half ? (p ? W23 : W13) : (p ? W22 : W12);
    scale = a0s3;
  }
  float val = Wsrc[u * 4096 + v * 64 + w] * scale;
  unsigned ub = __builtin_bit_cast(unsigned, val);
  ub += 0x7fffu + ((ub >> 16) & 1u);  // RTNE
  B[idx] = (u16)(ub >> 16);
}

// ---------------------------------------------------------------------------
// Main kernel: 128 threads = 2 waves, 64 edges/block (32/wave).
// Per wave: 4 M-tiles (out0, out1_0, out1_1, out1_2) x 2 N-tiles, 32x32x16 MFMA.
// ---------------------------------------------------------------------------
__global__ __launch_bounds__(128, 2)
void tp_main(const float* __restrict__ e1x, const float* __restrict__ e1y,
             const float* __restrict__ e2x, const float* __restrict__ e2y,
             const u16* __restrict__ B, float* __restrict__ out) {
  __shared__ u16 ylds[4 * 64 * 64];        // [ch][v][row]  32 KB, bf16
  __shared__ u16 blds[2][2 * 4 * 64 * 8];  // [buf][t][kq][w][8]  2 x 8 KB

  const int tid = threadIdx.x;
  const int wave = tid >> 6;
  const int lane = tid & 63;
  const int m = lane & 31;   // MFMA row/col within 32-tile
  const int hw = lane >> 5;  // half-wave -> k-octet select
  const int be0 = blockIdx.x * 64;
  const int e0 = be0 + wave * 32;
  const bool active = (e0 < ETOT);
  const int e = e0 + m;

  f32x16 acc[4][2] = {};  // [m-tile][n-tile]
  short8 xc[4][4];        // x cache: [ch][u-quarter], ch: x0, x1_0, x1_1, x1_2

  int buf = 0;
#pragma unroll 1
  for (int p = 0; p < 2; ++p) {
    const float* X = p ? e2x : e1x;
    const float* Y = p ? e2y : e1y;
    __syncthreads();  // previous pair's ylds reads complete

    // ---- stage y (block's 64 edges) into ylds[ch][v][row], bf16 ----
#pragma unroll 4
    for (int n = 0; n < 32; ++n) {
      int flat4 = n * 128 + tid;  // coalesced float4 index
      int r = flat4 >> 6;
      int c4 = flat4 & 63;
      if (be0 + r < ETOT) {
        float4 v4 = *(const float4*)(Y + (size_t)(be0 + r) * 256 + c4 * 4);
        float vv[4] = {v4.x, v4.y, v4.z, v4.w};
#pragma unroll
        for (int kk = 0; kk < 4; ++kk) {
          int d = c4 * 4 + kk;
          int ch, vi;
          if (d < 64) { ch = 0; vi = d; }
          else { int dd = d - 64; ch = 1 + dd % 3; vi = dd / 3; }
          ylds[(ch * 64 + vi) * 64 + r] =
              (u16)(__builtin_bit_cast(unsigned, vv[kk]) >> 16);
        }
      }
    }

    // ---- gather x into registers (bf16 packed), per lane: its u-slices ----
    if (active) {
#pragma unroll
      for (int q = 0; q < 4; ++q) {  // u = q*16 + hw*8 + j
        const float* px = X + (size_t)e * 256 + q * 16 + hw * 8;
        float4 a4 = *(const float4*)px;
        float4 b4 = *(const float4*)(px + 4);
        float f[8] = {a4.x, a4.y, a4.z, a4.w, b4.x, b4.y, b4.z, b4.w};
        xc[0][q] = pack8(f);
      }
#pragma unroll
      for (int i = 0; i < 3; ++i) {
        const float* px = X + (size_t)e * 256 + 64 + i;
#pragma unroll
        for (int q = 0; q < 4; ++q) {
          float f[8];
#pragma unroll
          for (int j = 0; j < 8; ++j) f[j] = px[(q * 16 + hw * 8 + j) * 3];
          xc[1 + i][q] = pack8(f);
        }
      }
    }

    // ---- B staging helper: slab = 32 k-values, both types: 8 KB ----
    auto stageB = [&](int kk0, int dstbuf) {
#pragma unroll
      for (int q = 0; q < 4; ++q) {
        int flat = q * 128 + tid;  // 0..511 : t(1) kq(2) w(6)
        int t = flat >> 8;
        int kq = (flat >> 6) & 3;
        int w = flat & 63;
        const uint4* g = (const uint4*)(B + (size_t)(t * 64 + w) * 16384 +
                                        p * 8192 + kk0 + kq * 8);
        *(uint4*)&blds[dstbuf][flat * 8] = *g;
      }
    };

    stageB(0, buf);
    __syncthreads();

#pragma unroll 1
    for (int s = 0; s < 256; ++s) {  // 256 slabs x 32 k = 8192 k per pair
      if (s < 255) stageB((s + 1) * 32, buf ^ 1);
      if (active) {
        const u16* bb = blds[buf];
#pragma unroll
        for (int ksub = 0; ksub < 2; ++ksub) {
          int kk = s * 32 + ksub * 16;  // k within pair
          int half = kk >> 12;
          int lv = (kk >> 6) & 63;   // v for this chunk
          int qx = (kk >> 4) & 3;    // u-quarter
          // y scalars for this v, all 4 channels (broadcast across half-waves)
          float ys[4];
#pragma unroll
          for (int ch = 0; ch < 4; ++ch)
            ys[ch] = bf2f(ylds[(ch * 64 + lv) * 64 + wave * 32 + m]);
          // B fragments: lane -> B[k = (ksub*2+hw)*8 + j][n = n0 + m]
          short8 bfrag[2][2];
#pragma unroll
          for (int tb = 0; tb < 2; ++tb)
#pragma unroll
            for (int n = 0; n < 2; ++n) {
              int slot = tb * 256 + (ksub * 2 + hw) * 64 + n * 32 + m;
              bfrag[tb][n] = *(const short8*)&bb[slot * 8];
            }
          // A fragments (z synthesis)
          short8 af[4];
          if (half == 0) {  // z = x0[u]*y_b[v]; b = y0 (t0) / y1_i (t_i)
            float xf[8];
            unpk8(xc[0][qx], xf);
            af[0] = scalepack(xf, ys[0]);
            af[1] = scalepack(xf, ys[1]);
            af[2] = scalepack(xf, ys[2]);
            af[3] = scalepack(xf, ys[3]);
          } else {  // t0: z110 = sum_i x1_i[u]*y1_i[v];  t_i: x1_i[u]*y0[v]
            float x0f[8], x1f[8], x2f[8];
            unpk8(xc[1][qx], x0f);
            unpk8(xc[2][qx], x1f);
            unpk8(xc[3][qx], x2f);
            float z[8];
#pragma unroll
            for (int j = 0; j < 8; ++j)
              z[j] = x0f[j] * ys[1] + x1f[j] * ys[2] + x2f[j] * ys[3];
            af[0] = pack8(z);
            af[1] = scalepack(x0f, ys[0]);
            af[2] = scalepack(x1f, ys[0]);
            af[3] = scalepack(x2f, ys[0]);
          }
#pragma unroll
          for (int t = 0; t < 4; ++t) {
            const int tb = t ? 1 : 0;
            acc[t][0] = __builtin_amdgcn_mfma_f32_32x32x16_bf16(
                af[t], bfrag[tb][0], acc[t][0], 0, 0, 0);
            acc[t][1] = __builtin_amdgcn_mfma_f32_32x32x16_bf16(
                af[t], bfrag[tb][1], acc[t][1], 0, 0, 0);
          }
        }
      }
      __syncthreads();
      buf ^= 1;
    }
  }

  // ---- epilogue: C/D layout col=lane&31, row=(reg&3)+8*(reg>>2)+4*hw ----
  if (active) {
#pragma unroll
    for (int t = 0; t < 4; ++t)
#pragma unroll
      for (int n0 = 0; n0 < 2; ++n0) {
        f32x16 c = acc[t][n0];
        int n = n0 * 32 + m;  // w index
#pragma unroll
        for (int r = 0; r < 16; ++r) {
          int row = (r & 3) + 8 * (r >> 2) + 4 * hw;
          int ee = e0 + row;
          size_t off;
          if (t == 0) off = (size_t)ee * 256 + n;                  // out0[w]
          else        off = (size_t)ee * 256 + 64 + n * 3 + (t - 1);  // out1[w][i]
          out[off] = c[r];
        }
      }
  }
}

extern "C" void kernel_launch(void* const* d_in, const int* in_sizes, int n_in,
                              void* d_out, int out_size, void* d_ws, size_t ws_size,
                              hipStream_t stream) {
  const float* e1x = (const float*)d_in[0];
  const float* e1y = (const float*)d_in[1];
  const float* e2x = (const float*)d_in[2];
  const float* e2y = (const float*)d_in[3];
  const size_t bElems = (size_t)2 * 64 * 16384;  // 2 MiElems bf16 = 4 MiB
  if (ws_size < bElems * sizeof(u16)) return;    // visible as absmax failure
  u16* B = (u16*)d_ws;
  prep_B<<<8192, 256, 0, stream>>>(
      (const float*)d_in[4], (const float*)d_in[5], (const float*)d_in[6],
      (const float*)d_in[7], (const float*)d_in[8], (const float*)d_in[9],
      (const float*)d_in[10], (const float*)d_in[11], B);
  tp_main<<<(ETOT + 63) / 64, 128, 0, stream>>>(e1x, e1y, e2x, e2y, B,
                                                (float*)d_out);
}